// Round 9
// baseline (115.346 us; speedup 1.0000x reference)
//
#include <hip/hip_runtime.h>

#define NB 4
#define NC 8
#define NLOC 524288        // H*W*D
#define TOPN 512
#define POST 100
#define NBIN 8192          // fallback histogram bins
#define SELBINS 4096       // select histogram bins
#define SCAP 2048          // survivor capacity for rank-count
#define WPI 2048           // waves per image (512 blocks x 4 waves)
#define SLOTW 16           // key slots per wave
#define KEYSPAN (WPI*SLOTW)   // 32768 slots/image
#define FB_CAP 16384
#define NMS_THR 0.6f
#define CAND_THR 0.05f

typedef unsigned long long ull;

// ---------------- workspace layout (fully rewritten each call; no memset) ----------------
// [0, 32768)          ovf_arr : NB*WPI u32
// [32768, 49152)      tk      : NB*TOPN u64
// [49152, 57344)      keep    : NB*TOPN i32 (valid slots written by nms_cls; invalid masked by val>0)
// [57344, 106496)     det     : NB*TOPN*6 f32 (valid slots written by nms_cls)
// [106496, 1155072)   keys    : NB*KEYSPAN u64 (zero-sentinel padded per wave-slot)
#define OFF_OVF  0
#define OFF_TK   32768
#define OFF_KEEP 49152
#define OFF_DET  57344
#define OFF_KEYS 106496

__device__ __forceinline__ float sigmoidf_(float x) {
    return 1.0f / (1.0f + __expf(-x));
}

// bin mapping: normal keys have score>0.5 (hi in (0x3F000000,0x3F800000]); dense
// (fallback-rebuilt) keys have score>0.05 -> coarser mapping from 0x3D000000.
__device__ __forceinline__ int binof_(ull k, bool dn) {
    const unsigned hi = (unsigned)(k >> 32);
    const int off = (int)hi - (dn ? 0x3D000000 : 0x3F000000);
    int bin = dn ? (off >> 14) : (off >> 11);
    if (off < 0) bin = 0;
    if (bin > SELBINS - 1) bin = SELBINS - 1;
    return bin;
}

// ---------------- Pass 1: gather — no LDS/atomics/barriers; zero-sentinel slots ----------------
__global__ __launch_bounds__(256) void gather_spec(const float* __restrict__ cls,
                                                   const float* __restrict__ ctr,
                                                   ull* __restrict__ keys,
                                                   unsigned int* __restrict__ ovf_arr) {
    const int b = blockIdx.y;
    const int lane = threadIdx.x & 63, wid = threadIdx.x >> 6;
    const int n0 = (blockIdx.x * 256 + threadIdx.x) * 4;

    const float4 cv = *(const float4*)(ctr + (size_t)b * NLOC + n0);
    float4 cl[NC];
    #pragma unroll
    for (int c = 0; c < NC; ++c)
        cl[c] = *(const float4*)(cls + ((size_t)b * NC + c) * NLOC + n0);

    unsigned hm = 0;
    #pragma unroll
    for (int j = 0; j < 4; ++j)
        #pragma unroll
        for (int c = 0; c < NC; ++c)
            if (((const float*)&cl[c])[j] > 0.0f) hm |= 1u << (j * 8 + c);

    ull k0 = 0, k1 = 0, k2 = 0, k3 = 0;
    int kc = 0;
    if (hm) {
        #pragma unroll
        for (int j = 0; j < 4; ++j) {
            if ((hm >> (j * 8)) & 0xffu) {
                const float sc = sigmoidf_(((const float*)&cv)[j]);
                #pragma unroll
                for (int c = 0; c < NC; ++c) {
                    if ((hm >> (j * 8 + c)) & 1u) {
                        const float p = sigmoidf_(((const float*)&cl[c])[j]) * sc;
                        if (p > 0.5f) {
                            const unsigned flat = (unsigned)((n0 + j) * NC + c);
                            const ull key = ((ull)__float_as_uint(p) << 32) | (unsigned)(~flat);
                            if (kc == 0) k0 = key;
                            else if (kc == 1) k1 = key;
                            else if (kc == 2) k2 = key;
                            else if (kc == 3) k3 = key;
                            ++kc;
                        }
                    }
                }
            }
        }
    }
    const ull m1 = __ballot(kc >= 1), m2 = __ballot(kc >= 2);
    const ull m3 = __ballot(kc >= 3), m4 = __ballot(kc >= 4);
    const ull lt = (1ull << lane) - 1ull;
    const unsigned pos = (unsigned)(__popcll(m1 & lt) + __popcll(m2 & lt) +
                                    __popcll(m3 & lt) + __popcll(m4 & lt));
    const unsigned tot = (unsigned)(__popcll(m1) + __popcll(m2) + __popcll(m3) + __popcll(m4));
    const ull mo = __ballot(kc > 4);
    const int wgid = blockIdx.x * 4 + wid;
    ull* kb = keys + ((size_t)b * WPI + wgid) * SLOTW;
    const int sc_ = (kc > 4) ? 4 : kc;
    if (sc_ >= 1 && pos + 0 < SLOTW) kb[pos + 0] = k0;
    if (sc_ >= 2 && pos + 1 < SLOTW) kb[pos + 1] = k1;
    if (sc_ >= 3 && pos + 2 < SLOTW) kb[pos + 2] = k2;
    if (sc_ >= 4 && pos + 3 < SLOTW) kb[pos + 3] = k3;
    // zero-sentinel the unused tail (disjoint lanes -> no race)
    const unsigned zstart = (tot > (unsigned)SLOTW) ? (unsigned)SLOTW : tot;
    if (lane >= 48) {
        const unsigned s = (unsigned)(lane - 48);
        if (s >= zstart) kb[s] = 0;
    }
    if (lane == 0)
        ovf_arr[b * WPI + wgid] = ((tot > (unsigned)SLOTW) || mo) ? 1u : 0u;
}

// ---------------- exact fallback rebuild (block-uniform; ~never runs) ----------------
__device__ void rebuild_(const float* __restrict__ cls, const float* __restrict__ ctr,
                         ull* __restrict__ kb, int b, int t,
                         unsigned* fhist, unsigned* lpos, int* cut_s, int* md_s, int* dense_s) {
    for (int i = t; i < NBIN; i += 1024) fhist[i] = 0;
    if (t == 0) *lpos = 0;
    __syncthreads();
    for (int n = t; n < NLOC; n += 1024) {
        const float scv = sigmoidf_(ctr[(size_t)b * NLOC + n]);
        #pragma unroll
        for (int cc = 0; cc < NC; ++cc) {
            const float x = cls[((size_t)b * NC + cc) * NLOC + n];
            if (x > -2.9444390f) {
                const float s = sigmoidf_(x);
                if (s > CAND_THR) atomicAdd(&fhist[__float_as_uint(s * scv) >> 17], 1u);
            }
        }
    }
    __syncthreads();
    if (t == 0) {
        unsigned cum = 0; int bin = 0;
        for (int i = NBIN - 1; i >= 0; --i) {
            cum += fhist[i];
            if (cum >= (unsigned)TOPN) { bin = i; break; }
        }
        *cut_s = bin;
    }
    __syncthreads();
    const unsigned cb2 = (unsigned)(*cut_s);
    for (int n = t; n < NLOC; n += 1024) {
        const float scv = sigmoidf_(ctr[(size_t)b * NLOC + n]);
        #pragma unroll
        for (int cc = 0; cc < NC; ++cc) {
            const float x = cls[((size_t)b * NC + cc) * NLOC + n];
            if (x > -2.9444390f) {
                const float s = sigmoidf_(x);
                if (s > CAND_THR) {
                    const unsigned bits = __float_as_uint(s * scv);
                    if ((bits >> 17) >= cb2) {
                        const unsigned pos = atomicAdd(lpos, 1u);
                        if (pos < (unsigned)FB_CAP)
                            kb[pos] = ((ull)bits << 32) | (unsigned)(~(unsigned)(n * NC + cc));
                    }
                }
            }
        }
    }
    __threadfence_block();
    __syncthreads();
    if (t == 0) {
        *md_s = (int)((*lpos < (unsigned)FB_CAP) ? *lpos : (unsigned)FB_CAP);
        *dense_s = 1;
    }
    __syncthreads();
}

// ---------------- Pass 2: top-512 select (1 block/image, 1024 threads) ----------------
__global__ __launch_bounds__(1024) void select_topk(const float* __restrict__ cls,
                                                    const float* __restrict__ ctr,
                                                    ull* __restrict__ keys,
                                                    const unsigned int* __restrict__ ovf_arr,
                                                    ull* __restrict__ tk_g) {
    __shared__ union SU {
        struct { union { unsigned hist[SELBINS]; int rank[SCAP]; } h; ull surv[SCAP]; } s; // 32KB
        unsigned fhist[NBIN];                                                              // 32KB
    } u;
    __shared__ ull tkl[TOPN];
    __shared__ unsigned redc[16];
    __shared__ unsigned scnt, tot_s, lpos;
    __shared__ int cut_s, dense_s, md_s;

    const int b = blockIdx.x, t = threadIdx.x;
    const int lane = t & 63, wid = t >> 6;
    ull* kb = keys + (size_t)b * KEYSPAN;

    // phase A: overflow reduce (independent loads, no per-element use)
    {
        unsigned o = ovf_arr[b * WPI + t] | ovf_arr[b * WPI + 1024 + t];
        #pragma unroll
        for (int d = 32; d >= 1; d >>= 1) o |= __shfl_down(o, d);
        if (lane == 0) redc[wid] = o;
    }
    if (t < TOPN) tkl[t] = 0;
    __syncthreads();
    if (t == 0) {
        unsigned ov = 0;
        #pragma unroll
        for (int w = 0; w < 16; ++w) ov |= redc[w];
        dense_s = ov ? 1 : 0;
        md_s = 0;
    }
    __syncthreads();
    if (dense_s) rebuild_(cls, ctr, kb, b, t, u.fhist, &lpos, &cut_s, &md_s, &dense_s);

    // phase B/C: histogram + cutoff scan (retry once via rebuild if total < 512)
    for (int pass = 0; pass < 2; ++pass) {
        for (int i = t; i < SELBINS; i += 1024) u.s.h.hist[i] = 0;
        if (t == 0) scnt = 0;
        __syncthreads();
        {
            const bool dn = (dense_s != 0);
            const int Md = md_s;
            for (int it = 0; it < KEYSPAN / 1024; ++it) {
                const int g = it * 1024 + t;
                const ull k = kb[g];
                const bool pred = dn ? (g < Md) : (k != 0ull);
                if (pred) atomicAdd(&u.s.h.hist[binof_(k, dn)], 1u);
            }
        }
        __syncthreads();
        if (t < 64) {
            unsigned s = 0;
            #pragma unroll 8
            for (int i = 0; i < 64; ++i)
                s += u.s.h.hist[t * 64 + ((i + t) & 63)];
            unsigned suf = s;
            #pragma unroll
            for (int d = 1; d < 64; d <<= 1) {
                const unsigned o = __shfl_down(suf, d);
                suf += (t + d < 64) ? o : 0u;
            }
            if (t == 0) tot_s = suf;
            const ull mask = __ballot(suf >= TOPN);
            unsigned nxt = __shfl_down(suf, 1);
            if (t == 63) nxt = 0;
            if (mask == 0ull) {
                if (t == 0) cut_s = 0;
            } else {
                const int L = 63 - __builtin_clzll(mask);
                if (t == L) {
                    unsigned cum = nxt;
                    int c = L * 64;
                    for (int i = 63; i >= 0; --i) {
                        cum += u.s.h.hist[L * 64 + i];
                        if (cum >= TOPN) { c = L * 64 + i; break; }
                    }
                    cut_s = c;
                }
            }
        }
        __syncthreads();
        if (tot_s >= (unsigned)TOPN || dense_s) break;
        rebuild_(cls, ctr, kb, b, t, u.fhist, &lpos, &cut_s, &md_s, &dense_s);
    }

    // phase D: wave-aggregated compact (predicate from value only)
    {
        const bool dn = (dense_s != 0);
        const int Md = md_s;
        const int cb = cut_s;
        for (int it = 0; it < KEYSPAN / 1024; ++it) {
            const int g = it * 1024 + t;
            const ull k = kb[g];
            bool pred = dn ? (g < Md) : (k != 0ull);
            pred = pred && (binof_(k, dn) >= cb);
            const ull mv = __ballot(pred);
            unsigned base = 0;
            if (lane == 0 && mv) base = atomicAdd(&scnt, (unsigned)__popcll(mv));
            base = __shfl(base, 0);
            if (pred) {
                const unsigned pos = base + (unsigned)__popcll(mv & ((1ull << lane) - 1ull));
                if (pos < (unsigned)SCAP) u.s.surv[pos] = k;
            }
        }
    }
    __syncthreads();

    const unsigned sc_f = scnt;
    if (sc_f <= (unsigned)SCAP) {
        const int S = (int)sc_f;
        // zero-pad survivors; zero rank accumulators (rank aliases dead hist)
        for (int i = S + t; i < SCAP; i += 1024) u.s.surv[i] = 0;
        for (int i = t; i < SCAP; i += 1024) u.s.h.rank[i] = 0;
        __syncthreads();
        // phase E: tiled register rank-count — (i-tile, j-tile) pairs over 16 waves
        const int NT = (S + 63) >> 6;
        for (int pid = wid; pid < NT * NT; pid += 16) {
            const int it_ = pid / NT, jt_ = pid - it_ * NT;
            const ull iv = u.s.surv[it_ * 64 + lane];
            const ull jv = u.s.surv[jt_ * 64 + lane];
            int r = 0;
            #pragma unroll
            for (int jj = 0; jj < 64; ++jj)
                r += (__shfl(jv, jj) > iv) ? 1 : 0;
            if (r) atomicAdd(&u.s.h.rank[it_ * 64 + lane], r);
        }
        __syncthreads();
        if (t < S) {
            const int r = u.s.h.rank[t];
            if (r < TOPN) tkl[r] = u.s.surv[t];
        }
        if (t + 1024 < S) {
            const int r = u.s.h.rank[t + 1024];
            if (r < TOPN) tkl[r] = u.s.surv[t + 1024];
        }
    } else {
        // pathological tie storm: exact global rank-count (never on this data)
        const bool dn = (dense_s != 0);
        const int Md = md_s;
        for (int i = t; i < KEYSPAN; i += 1024) {
            const ull k = kb[i];
            const bool v = dn ? (i < Md) : (k != 0ull);
            if (!v) continue;
            int r = 0;
            for (int j = 0; j < KEYSPAN; ++j) {
                const ull kj = kb[j];
                const bool vj = dn ? (j < Md) : (kj != 0ull);
                r += (vj && kj > k) ? 1 : 0;
            }
            if (r < TOPN) tkl[r] = k;
        }
    }
    __syncthreads();
    if (t < TOPN) tk_g[b * TOPN + t] = tkl[t];
}

__device__ __forceinline__ float iou3d_(const float* a, const float* bx) {
    const float ix = fminf(a[3], bx[3]) - fmaxf(a[0], bx[0]);
    const float iy = fminf(a[4], bx[4]) - fmaxf(a[1], bx[1]);
    const float iz = fminf(a[5], bx[5]) - fmaxf(a[2], bx[2]);
    const float inter = fmaxf(ix, 0.0f) * fmaxf(iy, 0.0f) * fmaxf(iz, 0.0f);
    const float v0 = fmaxf(a[3] - a[0], 0.0f) * fmaxf(a[4] - a[1], 0.0f) * fmaxf(a[5] - a[2], 0.0f);
    const float v1 = fmaxf(bx[3] - bx[0], 0.0f) * fmaxf(bx[4] - bx[1], 0.0f) * fmaxf(bx[5] - bx[2], 0.0f);
    return inter / (v0 + v1 - inter + 1e-9f);
}

// ---------------- Pass 3: per-(image,class) decode + NMS (32 blocks x 1 wave) ----------------
__global__ __launch_bounds__(64) void nms_cls(const ull* __restrict__ tk_g,
                                              const float* __restrict__ loc,
                                              const float* __restrict__ box,
                                              float* __restrict__ det_g,
                                              int* __restrict__ keep_g) {
    __shared__ ull tkl[TOPN];                 // 4KB
    __shared__ short mlist[TOPN];             // 1KB
    __shared__ float mbox[TOPN][6];           // 12KB
    __shared__ unsigned char sok[TOPN];
    __shared__ short clist2[TOPN];

    const int b = blockIdx.y, mycls = blockIdx.x + 1;
    const int lane = threadIdx.x;
    const ull lt = (1ull << lane) - 1ull;

    for (int j = lane; j < TOPN; j += 64) tkl[j] = tk_g[b * TOPN + j];
    __syncthreads();

    // prelim members: class match && score valid (in tk order)
    int cnt = 0;
    for (int j0 = 0; j0 < TOPN; j0 += 64) {
        const int j = j0 + lane;
        const ull k = tkl[j];
        const float val = __uint_as_float((unsigned)(k >> 32));
        const unsigned flat = ~(unsigned)(k & 0xffffffffu);
        const bool pred = (val > 0.0f) && ((int)(flat & 7u) + 1 == mycls);
        const ull m = __ballot(pred);
        if (pred) mlist[cnt + __popcll(m & lt)] = (short)j;
        cnt += __popcll(m);
    }
    __syncthreads();

    // decode members; side-check; write det + provisional keep
    for (int mm = lane; mm < cnt; mm += 64) {
        const int j = mlist[mm];
        const ull k = tkl[j];
        const unsigned flat = ~(unsigned)(k & 0xffffffffu);
        const int n = (int)(flat >> 3);
        const float lx = loc[n * 3 + 0], ly = loc[n * 3 + 1], lz = loc[n * 3 + 2];
        const float* bp = box + (size_t)b * 6 * NLOC + n;
        const float b0 = bp[0];
        const float b1 = bp[(size_t)NLOC];
        const float b2 = bp[2 * (size_t)NLOC];
        const float b3 = bp[3 * (size_t)NLOC];
        const float b4 = bp[4 * (size_t)NLOC];
        const float b5 = bp[5 * (size_t)NLOC];
        const float d0 = fminf(fmaxf(lx - b0, 0.0f), 255.0f);
        const float d1 = fminf(fmaxf(ly - b1, 0.0f), 255.0f);
        const float d2 = fminf(fmaxf(lz - b2, 0.0f), 63.0f);
        const float d3 = fminf(fmaxf(lx + b3, 0.0f), 255.0f);
        const float d4 = fminf(fmaxf(ly + b4, 0.0f), 255.0f);
        const float d5 = fminf(fmaxf(lz + b5, 0.0f), 63.0f);
        const bool ok = (d3 - d0 >= 0.0f) && (d4 - d1 >= 0.0f) && (d5 - d2 >= 0.0f);
        mbox[mm][0] = d0; mbox[mm][1] = d1; mbox[mm][2] = d2;
        mbox[mm][3] = d3; mbox[mm][4] = d4; mbox[mm][5] = d5;
        sok[mm] = ok ? 1 : 0;
        float* dp = det_g + (size_t)(b * TOPN + j) * 6;
        dp[0] = d0; dp[1] = d1; dp[2] = d2; dp[3] = d3; dp[4] = d4; dp[5] = d5;
        keep_g[b * TOPN + j] = ok ? 1 : 0;
    }
    __syncthreads();

    // final (side-ok) list, order-preserving
    int cnt2 = 0;
    for (int m0 = 0; m0 < cnt; m0 += 64) {
        const int mm = m0 + lane;
        const bool pred = (mm < cnt) && (sok[mm] != 0);
        const ull m = __ballot(pred);
        if (pred) clist2[cnt2 + __popcll(m & lt)] = (short)mm;
        cnt2 += __popcll(m);
    }
    __syncthreads();

    if (cnt2 <= 128) {
        // mask-path NMS (register sets, LDS broadcast pivots)
        const bool h0 = (lane < cnt2), h1 = (lane + 64 < cnt2);
        const int g0 = h0 ? clist2[lane] : 0;
        const int g1 = h1 ? clist2[lane + 64] : 0;
        float A0[6], A1[6];
        #pragma unroll
        for (int q = 0; q < 6; ++q) {
            A0[q] = h0 ? mbox[g0][q] : 0.0f;
            A1[q] = h1 ? mbox[g1][q] : 0.0f;
        }
        ull s0 = 0, s1lo = 0, s1hi = 0;
        for (int i = 0; i < cnt2; ++i) {
            const int gi = clist2[i];
            float pb[6];
            #pragma unroll
            for (int q = 0; q < 6; ++q) pb[q] = mbox[gi][q];
            if (i < 64) {
                if (h0 && lane > i && iou3d_(A0, pb) > NMS_THR) s0 |= 1ull << i;
                if (h1 && iou3d_(A1, pb) > NMS_THR) s1lo |= 1ull << i;
            } else {
                if (h1 && (i - 64) < lane && iou3d_(A1, pb) > NMS_THR) s1hi |= 1ull << (i - 64);
            }
        }
        bool a0 = h0, a1 = h1;
        ull m0 = __ballot(a0), m1 = __ballot(a1);
        for (int i = 0; i < cnt2; ++i) {
            const bool alive_i = (i < 64) ? ((m0 >> i) & 1ull) : ((m1 >> (i - 64)) & 1ull);
            if (!alive_i) continue;
            if (a0 && i < 64 && ((s0 >> i) & 1ull)) a0 = false;
            if (a1) {
                const bool sb = (i < 64) ? ((s1lo >> i) & 1ull) : ((s1hi >> (i - 64)) & 1ull);
                if (sb) a1 = false;
            }
            m0 = __ballot(a0); m1 = __ballot(a1);
        }
        if (h0 && !a0) keep_g[b * TOPN + mlist[g0]] = 0;
        if (h1 && !a1) keep_g[b * TOPN + mlist[g1]] = 0;
    } else {
        // general greedy (adversarial class skew only)
        volatile unsigned char* al = sok;
        for (int i = 0; i < cnt2; ++i) {
            const int mi = clist2[i];
            if (!al[mi]) continue;
            float pb[6];
            #pragma unroll
            for (int q = 0; q < 6; ++q) pb[q] = mbox[mi][q];
            for (int e = i + 1 + lane; e < cnt2; e += 64) {
                const int me = clist2[e];
                if (al[me]) {
                    float cbx[6];
                    #pragma unroll
                    for (int q = 0; q < 6; ++q) cbx[q] = mbox[me][q];
                    if (iou3d_(cbx, pb) > NMS_THR) al[me] = 0;
                }
            }
            __threadfence_block();
        }
        for (int mm = lane; mm < cnt; mm += 64)
            keep_g[b * TOPN + mlist[mm]] = sok[mm] ? 1 : 0;
    }
}

// ---------------- Pass 4: position-order rank + top-100 emit ----------------
__global__ __launch_bounds__(512) void emit_out(const ull* __restrict__ tk_g,
                                                const float* __restrict__ det_g,
                                                const int* __restrict__ keep_g,
                                                float* __restrict__ out) {
    __shared__ int keepl[TOPN];
    __shared__ float ssl[TOPN];
    __shared__ int scll[TOPN];
    __shared__ int wcnt[NC];
    const int b = blockIdx.x, t = threadIdx.x;
    const int lane = t & 63, w = t >> 6;

    const ull k = tk_g[b * TOPN + t];
    const float val = __uint_as_float((unsigned)(k >> 32));
    const unsigned flat = ~(unsigned)(k & 0xffffffffu);
    const int kp = (val > 0.0f && keep_g[b * TOPN + t] != 0) ? 1 : 0;
    keepl[t] = kp;
    ssl[t] = (val > 0.0f) ? sqrtf(val) : 0.0f;
    scll[t] = (int)(flat & 7u) + 1;
    __syncthreads();

    {
        const ull km = __ballot(keepl[t] != 0);
        if (lane == 0) wcnt[w] = __popcll(km);
    }
    __syncthreads();
    {
        const ull km = __ballot(keepl[t] != 0);
        int before = 0, total = 0;
        #pragma unroll
        for (int w2 = 0; w2 < NC; ++w2) {
            total += wcnt[w2];
            if (w2 < w) before += wcnt[w2];
        }
        const int myrank = before + __popcll(km & ((1ull << lane) - 1ull));

        float* fbox = out;                       // (B,100,6)
        float* fscore = out + NB * POST * 6;     // (B,100)
        float* flabel = out + NB * POST * 7;     // (B,100)
        float* fvalid = out + NB * POST * 8;     // (B,100)

        if (keepl[t] && myrank < POST) {
            const float* dp = det_g + (size_t)(b * TOPN + t) * 6;
            #pragma unroll
            for (int q = 0; q < 6; ++q) fbox[(b * POST + myrank) * 6 + q] = dp[q];
            fscore[b * POST + myrank] = ssl[t];
            flabel[b * POST + myrank] = (float)scll[t];
            fvalid[b * POST + myrank] = 1.0f;
        }
        const int tc = (total < POST) ? total : POST;
        if (t >= tc && t < POST) {
            #pragma unroll
            for (int q = 0; q < 6; ++q) fbox[(b * POST + t) * 6 + q] = 0.0f;
            fscore[b * POST + t] = 0.0f;
            flabel[b * POST + t] = 0.0f;
            fvalid[b * POST + t] = 0.0f;
        }
    }
}

extern "C" void kernel_launch(void* const* d_in, const int* in_sizes, int n_in,
                              void* d_out, int out_size, void* d_ws, size_t ws_size,
                              hipStream_t stream) {
    const float* location = (const float*)d_in[0];
    const float* cls_pred = (const float*)d_in[1];
    const float* box_pred = (const float*)d_in[2];
    const float* ctr_pred = (const float*)d_in[3];

    char* ws = (char*)d_ws;
    unsigned int* ovf  = (unsigned int*)(ws + OFF_OVF);
    ull*          tk   = (ull*)(ws + OFF_TK);
    int*          keep = (int*)(ws + OFF_KEEP);
    float*        det  = (float*)(ws + OFF_DET);
    ull*          keys = (ull*)(ws + OFF_KEYS);

    gather_spec<<<dim3(NLOC / 1024, NB), 256, 0, stream>>>(cls_pred, ctr_pred, keys, ovf);
    select_topk<<<NB, 1024, 0, stream>>>(cls_pred, ctr_pred, keys, ovf, tk);
    nms_cls<<<dim3(NC, NB), 64, 0, stream>>>(tk, location, box_pred, det, keep);
    emit_out<<<NB, 512, 0, stream>>>(tk, det, keep, (float*)d_out);
}